// Round 9
// baseline (683.772 us; speedup 1.0000x reference)
//
#include <hip/hip_runtime.h>

typedef unsigned short ushort_t;
typedef __attribute__((ext_vector_type(8))) short short8;
typedef __attribute__((ext_vector_type(4))) short bf16x4;
typedef __attribute__((ext_vector_type(4))) float f32x4;

#define B_  4
#define T_  2048
#define D_  1024
#define NH  16
#define DK  64
#define DF_ 4096

__device__ __forceinline__ float bf2f(ushort_t u) {
    union { unsigned int i; float f; } c; c.i = ((unsigned int)u) << 16; return c.f;
}
__device__ __forceinline__ ushort_t f2bf(float f) {
    union { float f; unsigned int i; } c; c.f = f;
    unsigned int x = c.i;
    unsigned int r = (x + 0x7fffu + ((x >> 16) & 1u)) >> 16;
    return (ushort_t)r;
}
__device__ __forceinline__ unsigned int fbits(float f) {
    union { float f; unsigned int i; } c; c.f = f; return c.i;
}

__device__ __forceinline__ f32x4 mfma_16x16x16_bf16(bf16x4 a, bf16x4 b, f32x4 c) {
#if __has_builtin(__builtin_amdgcn_mfma_f32_16x16x16bf16_1k)
    return __builtin_amdgcn_mfma_f32_16x16x16bf16_1k(a, b, c, 0, 0, 0);
#else
    f32x4 d;
    asm("v_mfma_f32_16x16x16_bf16 %0, %1, %2, %3" : "=v"(d) : "v"(a), "v"(b), "v"(c));
    return d;
#endif
}

#define AS1(p) ((const __attribute__((address_space(1))) void*)(p))
#define AS3(p) ((__attribute__((address_space(3))) void*)(p))

__device__ __forceinline__ void barrier_raw() {
    asm volatile("" ::: "memory");
    __builtin_amdgcn_s_barrier();
    asm volatile("" ::: "memory");
}

// ---------------- fp32 -> bf16 convert: 3 segments in one launch ----------------
__global__ __launch_bounds__(256) void convert3(const float* __restrict__ s0, ushort_t* __restrict__ d0, int nb0,
                                                const float* __restrict__ s1, ushort_t* __restrict__ d1, int nb1,
                                                const float* __restrict__ s2, ushort_t* __restrict__ d2) {
    int b = blockIdx.x;
    const float* s; ushort_t* d;
    if (b < nb0)            { s = s0; d = d0; }
    else if (b < nb0 + nb1) { s = s1; d = d1; b -= nb0; }
    else                    { s = s2; d = d2; b -= nb0 + nb1; }
    const int i = (b * 256 + threadIdx.x) * 4;
    const float4 v = *(const float4*)(s + i);
    d[i + 0] = f2bf(v.x);
    d[i + 1] = f2bf(v.y);
    d[i + 2] = f2bf(v.z);
    d[i + 3] = f2bf(v.w);
}

// ---------------- LayerNorm: one block per row (D=1024), fp32 in, bf16 out ----------------
__global__ __launch_bounds__(256) void ln_kernel(const float* __restrict__ x,
                                                 const float* __restrict__ g,
                                                 const float* __restrict__ be,
                                                 ushort_t* __restrict__ out) {
    const int row = blockIdx.x, tid = threadIdx.x;
    float v[4];
    #pragma unroll
    for (int j = 0; j < 4; ++j) v[j] = x[(size_t)row * D_ + tid + j * 256];
    float s = v[0] + v[1] + v[2] + v[3];
    #pragma unroll
    for (int o = 32; o > 0; o >>= 1) s += __shfl_xor(s, o);
    __shared__ float red1[4], red2[4];
    const int wid = tid >> 6, lane = tid & 63;
    if (lane == 0) red1[wid] = s;
    __syncthreads();
    const float mean = (red1[0] + red1[1] + red1[2] + red1[3]) * (1.0f / D_);
    float ss = 0.0f;
    #pragma unroll
    for (int j = 0; j < 4; ++j) { float d = v[j] - mean; ss += d * d; }
    #pragma unroll
    for (int o = 32; o > 0; o >>= 1) ss += __shfl_xor(ss, o);
    if (lane == 0) red2[wid] = ss;
    __syncthreads();
    const float var = (red2[0] + red2[1] + red2[2] + red2[3]) * (1.0f / D_);
    const float rs = rsqrtf(var + 1e-5f);
    #pragma unroll
    for (int j = 0; j < 4; ++j) {
        const int col = tid + j * 256;
        out[(size_t)row * D_ + col] = f2bf((v[j] - mean) * rs * g[col] + be[col]);
    }
}

// ---------------- GEMM 128x128, BK=32, 3 blocks/CU, counted lookahead, swizzled LDS ----------------
// C[M,Nn] = A[M,K] * W[Nn,K]^T + bias.  256 threads = 4 waves (2M x 2N); per-wave out 64x64.
// LDS: A 2x[128][32] + B 2x[128][32] bf16 = 32 KB -> LDS allows 5 blocks/CU;
// __launch_bounds__(256,3) caps VGPR at 170 -> 3 blocks/CU, 12 waves/CU (m114-style
// inter-block overlap hides DS<->MFMA serialization that bound the 2-block configs).
// Per K-tile: MFMA x16 (setprio) ; vmcnt(0) (drains tile t+1, issued a FULL tile earlier) ;
// barrier ; ds_read 8 frags(t+1) ; STAGE4(t+2).  One barrier + one vmcnt per tile.
// Swizzle: 16B chunk c of row r stores global chunk c^((r>>1)&3); readers XOR the same
// (uniform slot distribution mod 128B -> conflict-free b128 reads for 64-B rows).
// EPI: 0 = bf16 out; 1 = gelu bf16 out; 2/5 = +f32 resid, f32 out; 3 = +f32 resid+bias f32 out
template<int EPI>
__global__ __launch_bounds__(256, 3) void gemm128(const ushort_t* __restrict__ A, int lda,
                                                  const ushort_t* __restrict__ W, int ldw,
                                                  const float* __restrict__ bias,
                                                  const float* __restrict__ resid,
                                                  void* __restrict__ Cout,
                                                  int Nn, int K, int ntn) {
    __shared__ ushort_t As[2 * 128 * 32];
    __shared__ ushort_t Bs[2 * 128 * 32];
    const int tid = threadIdx.x;
    // bijective XCD swizzle (all grids are multiples of 8)
    const int nwg = gridDim.x;
    int wg = blockIdx.x;
    wg = (wg & 7) * (nwg >> 3) + (wg >> 3);
    const int m0 = (wg / ntn) * 128, n0 = (wg % ntn) * 128;

    const int w = tid >> 6, lane = tid & 63;
    const int quad = lane >> 4, l15 = lane & 15;
    const int wr = (w >> 1) * 64, wc = (w & 1) * 64;
    // reader chunk: global chunk `quad` of row r lives at LDS chunk quad^((r>>1)&3);
    // r = (64-mult) + l15  =>  (r>>1)&3 == (l15>>1)&3  (lane-constant)
    const int cq = quad ^ ((l15 >> 1) & 3);

    // staging: L = g*256+tid covers row L>>2, chunk L&3 (4 chunks per 64-B row)
    const ushort_t* pA[2];
    const ushort_t* pB[2];
    #pragma unroll
    for (int g = 0; g < 2; ++g) {
        const int L = g * 256 + tid;
        const int row = L >> 2, c = L & 3;
        const int csw = c ^ ((row >> 1) & 3);
        pA[g] = A + (size_t)(m0 + row) * lda + csw * 8;
        pB[g] = W + (size_t)(n0 + row) * ldw + csw * 8;
    }

#define SA(bb, g, kk) __builtin_amdgcn_global_load_lds(AS1(pA[g] + (kk)), \
        AS3(As + (size_t)(bb) * 4096 + (g) * 2048 + (size_t)tid * 8), 16, 0, 0)
#define SB(bb, g, kk) __builtin_amdgcn_global_load_lds(AS1(pB[g] + (kk)), \
        AS3(Bs + (size_t)(bb) * 4096 + (g) * 2048 + (size_t)tid * 8), 16, 0, 0)
#define STAGE4(bb, kk) do { SA(bb, 0, kk); SA(bb, 1, kk); SB(bb, 0, kk); SB(bb, 1, kk); } while (0)
#define DSRALL(bb) do { \
    const ushort_t* Ab_ = As + (bb) * 4096; \
    const ushort_t* Bb_ = Bs + (bb) * 4096; \
    _Pragma("unroll") \
    for (int ni = 0; ni < 4; ++ni) b[ni] = *(const short8*)(Bb_ + (size_t)(wc + ni * 16 + l15) * 32 + cq * 8); \
    _Pragma("unroll") \
    for (int mi = 0; mi < 4; ++mi) a[mi] = *(const short8*)(Ab_ + (size_t)(wr + mi * 16 + l15) * 32 + cq * 8); \
  } while (0)
#define MFMA16() do { \
    __builtin_amdgcn_s_setprio(1); \
    _Pragma("unroll") \
    for (int mi = 0; mi < 4; ++mi) \
      _Pragma("unroll") \
      for (int ni = 0; ni < 4; ++ni) \
        acc[mi][ni] = __builtin_amdgcn_mfma_f32_16x16x32_bf16(a[mi], b[ni], acc[mi][ni], 0, 0, 0); \
    __builtin_amdgcn_s_setprio(0); \
  } while (0)

    f32x4 acc[4][4] = {};
    const int NT = K >> 5;

    short8 a[4], b[4];

    // prologue: stage tile0, sync, read its frags, stage tile1
    STAGE4(0, 0);
    asm volatile("s_waitcnt vmcnt(0)" ::: "memory");
    __builtin_amdgcn_sched_barrier(0);
    barrier_raw();
    DSRALL(0);
    if (NT > 1) STAGE4(1, 32);

    for (int kt = 0; kt < NT; ++kt) {
        MFMA16();
        if (kt + 1 < NT) {
            // STAGE4(kt+1) was issued a full K-tile ago -> drain is latency-covered
            asm volatile("s_waitcnt vmcnt(0)" ::: "memory");
            __builtin_amdgcn_sched_barrier(0);
            barrier_raw();   // all waves done reading buf kt&1; tile kt+1 writes visible
            DSRALL((kt + 1) & 1);
            if (kt + 2 < NT) STAGE4(kt & 1, (size_t)(kt + 2) * 32);
        }
    }

#undef SA
#undef SB
#undef STAGE4
#undef DSRALL
#undef MFMA16

    // ---- epilogue ----
    #pragma unroll
    for (int ni = 0; ni < 4; ++ni) {
        const int col = n0 + wc + ni * 16 + l15;
        const float bv = (EPI == 5) ? 0.0f : bias[col];
        #pragma unroll
        for (int mi = 0; mi < 4; ++mi) {
            #pragma unroll
            for (int r = 0; r < 4; ++r) {
                const int rowg = m0 + wr + mi * 16 + quad * 4 + r;
                const size_t idx = (size_t)rowg * Nn + col;
                float v = acc[mi][ni][r] + bv;
                if (EPI == 1) {
                    // tanh-GELU via exp2: 0.5*(1+tanh(y)) = u/(u+1), u=e^{2y}
                    const float y = 0.7978845608028654f * (v + 0.044715f * v * v * v);
                    const float u = exp2f(fminf(2.8853900817779268f * y, 80.0f));
                    v = v * u * __builtin_amdgcn_rcpf(u + 1.0f);
                }
                if (EPI == 2 || EPI == 5 || EPI == 3) {
                    v += resid[idx];
                    ((float*)Cout)[idx] = v;
                } else {
                    ((ushort_t*)Cout)[idx] = f2bf(v);
                }
            }
        }
    }
}

// ---------------- RoPE on q,k + V transpose, reading stacked qkv [M,3072] ----------------
#define QSCL 0.18033688011112042f   // 0.125 * log2(e)
__global__ __launch_bounds__(256) void rope_reorder(const ushort_t* __restrict__ qkv,
                                                    ushort_t* __restrict__ q_rot,
                                                    ushort_t* __restrict__ k_rot,
                                                    ushort_t* __restrict__ v_t) {
    const int LD = 3 * D_;
    const int tt = blockIdx.x, h = blockIdx.y, b = blockIdx.z;
    const int t0 = tt * 64, tid = threadIdx.x;
    const int r = tid >> 2, c = tid & 3;
    const int t = t0 + r;
    const size_t src = ((size_t)(b * T_ + t)) * LD + h * DK + c * 16;
    const size_t dst = (((size_t)(b * NH + h)) * T_ + t) * DK + c * 16;
    #pragma unroll
    for (int j = 0; j < 8; ++j) {
        const int i = c * 8 + j;  // pair index 0..31
        const float theta = expf(-(float)(2 * i) * (1.0f / DK) * 9.210340371976184f);
        const float ang = (float)t * theta;
        float sn, cs;
        sincosf(ang, &sn, &cs);
        {
            float x1 = bf2f(qkv[src + 2 * j]), x2 = bf2f(qkv[src + 2 * j + 1]);
            q_rot[dst + 2 * j]     = f2bf((x1 * cs - x2 * sn) * QSCL);
            q_rot[dst + 2 * j + 1] = f2bf((x1 * sn + x2 * cs) * QSCL);
        }
        {
            float x1 = bf2f(qkv[src + D_ + 2 * j]), x2 = bf2f(qkv[src + D_ + 2 * j + 1]);
            k_rot[dst + 2 * j]     = f2bf(x1 * cs - x2 * sn);
            k_rot[dst + 2 * j + 1] = f2bf(x1 * sn + x2 * cs);
        }
    }
    // V transpose via LDS
    __shared__ ushort_t vs[64][72];
    #pragma unroll
    for (int j = 0; j < 16; ++j)
        vs[r][c * 16 + j] = qkv[((size_t)(b * T_ + t)) * LD + 2 * D_ + h * DK + c * 16 + j];
    __syncthreads();
    const int d = tid >> 2, tc = (tid & 3) * 16;
    const size_t vdst = (((size_t)(b * NH + h)) * DK + d) * T_ + t0 + tc;
    #pragma unroll
    for (int j = 0; j < 16; ++j)
        v_t[vdst + j] = vs[tc + j][d];
}

// ---------------- Flash attention: LDS-staged K/V, QBLK=128 (2 q-subtiles/wave) ----------------
__device__ __forceinline__ void softmax_tile(f32x4 (&st)[8], f32x4 (&oc)[4],
                                             float& mrow, float& lrow,
                                             unsigned int (&pk)[8][2]) {
    float mt[8];
    #pragma unroll
    for (int tl = 0; tl < 8; ++tl)
        mt[tl] = fmaxf(fmaxf(st[tl][0], st[tl][1]), fmaxf(st[tl][2], st[tl][3]));
    float mloc = fmaxf(fmaxf(fmaxf(mt[0], mt[1]), fmaxf(mt[2], mt[3])),
                       fmaxf(fmaxf(mt[4], mt[5]), fmaxf(mt[6], mt[7])));
    mloc = fmaxf(mloc, __shfl_xor(mloc, 16));
    mloc = fmaxf(mloc, __shfl_xor(mloc, 32));

    // defer-max: only rescale when the running max grew by >8 (log2 units)
    if (!__all(mloc <= mrow + 8.0f)) {
        const float mnew = fmaxf(mrow, mloc);
        const float al = exp2f(mrow - mnew);
        lrow *= al;
        #pragma unroll
        for (int ci = 0; ci < 4; ++ci)
            #pragma unroll
            for (int r = 0; r < 4; ++r) oc[ci][r] *= al;
        mrow = mnew;
    }

    float ps0 = 0.0f, ps1 = 0.0f;
    #pragma unroll
    for (int tl = 0; tl < 8; ++tl) {
        float p0 = exp2f(st[tl][0] - mrow);
        float p1 = exp2f(st[tl][1] - mrow);
        float p2 = exp2f(st[tl][2] - mrow);
        float p3 = exp2f(st[tl][3] - mrow);
        if (tl & 1) ps1 += (p0 + p1) + (p2 + p3);
        else        ps0 += (p0 + p1) + (p2 + p3);
        pk[tl][0] = (fbits(p1) & 0xFFFF0000u) | (fbits(p0) >> 16);
        pk[tl][1] = (fbits(p3) & 0xFFFF0000u) | (fbits(p2) >> 16);
    }
    float ps = ps0 + ps1;
    ps += __shfl_xor(ps, 16);
    ps += __shfl_xor(ps, 32);
    lrow += ps;
}

__global__ __launch_bounds__(256) void flash_attn(const ushort_t* __restrict__ q,
                                                  const ushort_t* __restrict__ k,
                                                  const ushort_t* __restrict__ vt,
                                                  ushort_t* __restrict__ ctx) {
    __shared__ ushort_t Ks[2 * 128 * 64];
    __shared__ ushort_t Vs[2 * 64 * 128];
    const int qt = blockIdx.x, h = blockIdx.y, b = blockIdx.z;
    const int tid = threadIdx.x, w = tid >> 6, lane = tid & 63;
    const int quad = lane >> 4, l15 = lane & 15;
    const int q0 = qt * 128;
    const size_t bh = (size_t)(b * NH + h);
    const ushort_t* qp = q + bh * T_ * DK;
    const ushort_t* kp = k + bh * T_ * DK;
    const ushort_t* vp = vt + bh * DK * T_;

    short8 qf[2][2];
    #pragma unroll
    for (int s = 0; s < 2; ++s)
        #pragma unroll
        for (int kk = 0; kk < 2; ++kk)
            qf[s][kk] = *(const short8*)(qp + (size_t)(q0 + w * 32 + s * 16 + l15) * DK + kk * 32 + quad * 8);

    f32x4 oc0[4] = {}, oc1[4] = {};
    float m0r = -INFINITY, l0r = 0.0f, m1r = -INFINITY, l1r = 0.0f;

    // staging source pointers (swizzle XOR is loop-invariant: rows advance by 128 == 0 mod 8)
    const ushort_t* ksp[4];
    const ushort_t* vsp[4];
    #pragma unroll
    for (int rr = 0; rr < 4; ++rr) {
        const int L = rr * 256 + tid;
        const int krow = L >> 3, kc = L & 7;
        ksp[rr] = kp + (size_t)krow * DK + ((kc ^ (krow & 7)) << 3);
        const int vrow = L >> 4, vc = L & 15;
        const int vsc = (vc & 8) | ((vc & 7) ^ (vrow & 7));
        vsp[rr] = vp + (size_t)vrow * T_ + (vsc << 3);
    }

#define STAGE(bufi) do {                                                                  \
        ushort_t* kb = Ks + (bufi) * (128 * 64);                                          \
        ushort_t* vb = Vs + (bufi) * (64 * 128);                                          \
        _Pragma("unroll")                                                                 \
        for (int rr = 0; rr < 4; ++rr) {                                                  \
            const int L = rr * 256 + tid;                                                 \
            __builtin_amdgcn_global_load_lds(AS1(ksp[rr]), AS3(kb + (size_t)L * 8), 16, 0, 0); \
            __builtin_amdgcn_global_load_lds(AS1(vsp[rr]), AS3(vb + (size_t)L * 8), 16, 0, 0); \
        }                                                                                 \
    } while (0)
#define ADVANCE() do {                                                                    \
        _Pragma("unroll")                                                                 \
        for (int rr = 0; rr < 4; ++rr) { ksp[rr] += 128 * DK; vsp[rr] += 128; }           \
    } while (0)

    STAGE(0); ADVANCE();
    __syncthreads();   // drains vmcnt(0) + barrier (compiler-inserted)

    int cur = 0;
    for (int it = 0; it < T_ / 128; ++it) {
        if (it + 1 < T_ / 128) { STAGE(cur ^ 1); ADVANCE(); }

        const ushort_t* kbase = Ks + cur * (128 * 64);
        const ushort_t* vbase = Vs + cur * (64 * 128);

        // QK^T: each K fragment read once, feeds both q-subtiles
        f32x4 st0[8], st1[8];
        __builtin_amdgcn_s_setprio(1);
        #pragma unroll
        for (int tl = 0; tl < 8; ++tl) {
            const int kvr = tl * 16 + l15;
            const int r7 = kvr & 7;
            const ushort_t* krow = kbase + (size_t)kvr * 64;
            short8 a0 = *(const short8*)(krow + ((quad ^ r7) << 3));
            short8 a1 = *(const short8*)(krow + (((quad + 4) ^ r7) << 3));
            f32x4 z0 = {};
            z0 = __builtin_amdgcn_mfma_f32_16x16x32_bf16(a0, qf[0][0], z0, 0, 0, 0);
            st0[tl] = __builtin_amdgcn_mfma_f32_16x16x32_bf16(a1, qf[0][1], z0, 0, 0, 0);
            f32x4 z1 = {};
            z1 = __builtin_amdgcn_mfma_f32_16x16x32_bf16(a0, qf[1][0], z1, 0, 0, 0);
            st1[tl] = __builtin_amdgcn_mfma_f32_16x16x32_bf16(a1, qf[1][1], z1, 0, 0, 0);
        }
        __builtin_amdgcn_s_setprio(0);

        unsigned int pk0[8][2], pk1[8][2];
        softmax_tile(st0, oc0, m0r, l0r, pk0);
        softmax_tile(st1, oc1, m1r, l1r, pk1);

        // PV: each V fragment read once, feeds both q-subtiles
        __builtin_amdgcn_s_setprio(1);
        #pragma unroll
        for (int t4 = 0; t4 < 8; ++t4) {
            union { unsigned int u[2]; bf16x4 v; } pb0, pb1;
            pb0.u[0] = pk0[t4][0]; pb0.u[1] = pk0[t4][1];
            pb1.u[0] = pk1[t4][0]; pb1.u[1] = pk1[t4][1];
            bf16x4 va[4];
            const int g = 2 * t4 + (quad >> 1);
            #pragma unroll
            for (int ci = 0; ci < 4; ++ci) {
                const int dd = ci * 16 + l15;
                const int sc = (g & 8) | ((g & 7) ^ (dd & 7));
                va[ci] = *(const bf16x4*)(vbase + (size_t)dd * 128 + (sc << 3) + ((quad & 1) << 2));
            }
            #pragma unroll
            for (int ci = 0; ci < 4; ++ci) {
                oc0[ci] = mfma_16x16x16_bf16(va[ci], pb0.v, oc0[ci]);
                oc1[ci] = mfma_16x16x16_bf16(va[ci], pb1.v, oc1[ci]);
            }
        }
        __builtin_amdgcn_s_setprio(0);

        __syncthreads();   // next-tile stage landed; all reads of cur done before overwrite
        cur ^= 1;
    }
#undef STAGE
#undef ADVANCE

    const float inv0 = 1.0f / l0r;
    const float inv1 = 1.0f / l1r;
    ushort_t* cb0 = ctx + (size_t)(b * T_ + q0 + w * 32 + l15) * D_ + h * DK + quad * 4;
    ushort_t* cb1 = ctx + (size_t)(b * T_ + q0 + w * 32 + 16 + l15) * D_ + h * DK + quad * 4;
    #pragma unroll
    for (int ci = 0; ci < 4; ++ci) {
        unsigned int u0 = ((unsigned int)f2bf(oc0[ci][0] * inv0)) | (((unsigned int)f2bf(oc0[ci][1] * inv0)) << 16);
        unsigned int u1 = ((unsigned int)f2bf(oc0[ci][2] * inv0)) | (((unsigned int)f2bf(oc0[ci][3] * inv0)) << 16);
        *(uint2*)(cb0 + ci * 16) = make_uint2(u0, u1);
        unsigned int u2 = ((unsigned int)f2bf(oc1[ci][0] * inv1)) | (((unsigned int)f2bf(oc1[ci][1] * inv1)) << 16);
        unsigned int u3 = ((unsigned int)f2bf(oc1[ci][2] * inv1)) | (((unsigned int)f2bf(oc1[ci][3] * inv1)) << 16);
        *(uint2*)(cb1 + ci * 16) = make_uint2(u2, u3);
    }
}

extern "C" void kernel_launch(void* const* d_in, const int* in_sizes, int n_in,
                              void* d_out, int out_size, void* d_ws, size_t ws_size,
                              hipStream_t stream) {
    const float* x   = (const float*)d_in[0];
    const float* Wq  = (const float*)d_in[2];
    const float* bq  = (const float*)d_in[3];
    const float* Wk  = (const float*)d_in[4];
    const float* bk  = (const float*)d_in[5];
    const float* Wv  = (const float*)d_in[6];
    const float* bv  = (const float*)d_in[7];
    const float* Wo  = (const float*)d_in[8];
    const float* bo  = (const float*)d_in[9];
    const float* W1  = (const float*)d_in[10];
    const float* b1  = (const float*)d_in[11];
    const float* W2  = (const float*)d_in[12];
    const float* b2  = (const float*)d_in[13];
    const float* g1  = (const float*)d_in[14];
    const float* be1 = (const float*)d_in[15];
    const float* g2  = (const float*)d_in[16];
    const float* be2 = (const float*)d_in[17];
    float* out = (float*)d_out;

    // ---- 96 MiB workspace layout ----
    // [0,48)  qkv_lin (48MB) -> ctx[0,16) + x2[16,48) after rope
    // [48,54) Wqkv_b (6MB, dead after QKV gemm) -> q_rot[48,64) -> Wo_b[48,50) -> ff[48,80)
    // [64,80) k_rot -> ff upper
    // [80,96) v_t -> W1_b[80,88) + W2_b[88,96)
    char* ws = (char*)d_ws;
    const size_t MB = 1024 * 1024;
    ushort_t* qkv_lin = (ushort_t*)(ws + 0 * MB);
    ushort_t* ctx     = (ushort_t*)(ws + 0 * MB);
    float*    x2      = (float*)   (ws + 16 * MB);
    ushort_t* Wqkv_b  = (ushort_t*)(ws + 48 * MB);
    ushort_t* q_rot   = (ushort_t*)(ws + 48 * MB);
    ushort_t* k_rot   = (ushort_t*)(ws + 64 * MB);
    ushort_t* v_t     = (ushort_t*)(ws + 80 * MB);
    ushort_t* Wo_b    = (ushort_t*)(ws + 48 * MB);
    ushort_t* ff      = (ushort_t*)(ws + 48 * MB);
    ushort_t* W1_b    = (ushort_t*)(ws + 80 * MB);
    ushort_t* W2_b    = (ushort_t*)(ws + 88 * MB);
    ushort_t* h1      = (ushort_t*)d_out;
    ushort_t* h2      = (ushort_t*)d_out;

    const int M = B_ * T_;
    const int DD = D_ * D_, DFD = DF_ * D_;

    // Phase A: LN1 + fused QKV (N=3072, stacked weights) — one convert launch for Wq/Wk/Wv
    convert3<<<3 * (DD / 1024), 256, 0, stream>>>(Wq, Wqkv_b, DD / 1024,
                                                  Wk, Wqkv_b + DD, DD / 1024,
                                                  Wv, Wqkv_b + 2 * DD);
    ln_kernel<<<M, 256, 0, stream>>>(x, g1, be1, h1);
    {
        float* bqkv = (float*)(ws + 54 * MB);  // 12 KB, dead after QKV gemm
        hipMemcpyAsync(bqkv,           bq, D_ * sizeof(float), hipMemcpyDeviceToDevice, stream);
        hipMemcpyAsync(bqkv + D_,      bk, D_ * sizeof(float), hipMemcpyDeviceToDevice, stream);
        hipMemcpyAsync(bqkv + 2 * D_,  bv, D_ * sizeof(float), hipMemcpyDeviceToDevice, stream);
        // grid 24*64 = 1536 blocks (%8==0)
        gemm128<0><<<(3072 / 128) * (M / 128), 256, 0, stream>>>(h1, D_, Wqkv_b, D_, bqkv, nullptr, qkv_lin, 3 * D_, D_, 3072 / 128);
    }

    // Phase B: RoPE + reorder (overwrites Wqkv_b region — dead)
    rope_reorder<<<dim3(T_ / 64, NH, B_), 256, 0, stream>>>(qkv_lin, q_rot, k_rot, v_t);

    // Phase C: attention (ctx overwrites qkv_lin lower 16MB — dead)
    flash_attn<<<dim3(T_ / 128, NH, B_), 256, 0, stream>>>(q_rot, k_rot, v_t, ctx);

    // Phase D: out-proj + residual; convert Wo/W1/W2 in ONE launch (v_t dead after flash)
    convert3<<<DD / 1024 + 2 * (DFD / 1024), 256, 0, stream>>>(Wo, Wo_b, DD / 1024,
                                                               W1, W1_b, DFD / 1024,
                                                               W2, W2_b);
    // grid 8*64 = 512 blocks (%8==0)
    gemm128<2><<<(D_ / 128) * (M / 128), 256, 0, stream>>>(ctx, D_, Wo_b, D_, bo, x, x2, D_, D_, D_ / 128);

    // Phase E: LN2
    ln_kernel<<<M, 256, 0, stream>>>(x2, g2, be2, h2);

    // Phase F: FFN in two DF halves (ff over q_rot/k_rot — dead)
    const int HF = DF_ / 2;
    // FFN1 halves: 16*64 = 1024 blocks; FFN2 halves: 8*64 = 512
    gemm128<1><<<(HF / 128) * (M / 128), 256, 0, stream>>>(h2, D_, W1_b, D_, b1, nullptr, ff, HF, D_, HF / 128);
    gemm128<5><<<(D_ / 128) * (M / 128), 256, 0, stream>>>(ff, HF, W2_b, DF_, nullptr, x2, x2, D_, HF, D_ / 128);
    gemm128<1><<<(HF / 128) * (M / 128), 256, 0, stream>>>(h2, D_, W1_b + (size_t)HF * D_, D_, b1 + HF, nullptr, ff, HF, D_, HF / 128);
    gemm128<3><<<(D_ / 128) * (M / 128), 256, 0, stream>>>(ff, HF, W2_b + HF, DF_, b2, x2, out, D_, HF, D_ / 128);
}

// Round 10
// 619.832 us; speedup vs baseline: 1.1032x; 1.1032x over previous
//
#include <hip/hip_runtime.h>

typedef unsigned short ushort_t;
typedef __attribute__((ext_vector_type(8))) short short8;
typedef __attribute__((ext_vector_type(4))) short bf16x4;
typedef __attribute__((ext_vector_type(4))) float f32x4;

#define B_  4
#define T_  2048
#define D_  1024
#define NH  16
#define DK  64
#define DF_ 4096

__device__ __forceinline__ float bf2f(ushort_t u) {
    union { unsigned int i; float f; } c; c.i = ((unsigned int)u) << 16; return c.f;
}
__device__ __forceinline__ ushort_t f2bf(float f) {
    union { float f; unsigned int i; } c; c.f = f;
    unsigned int x = c.i;
    unsigned int r = (x + 0x7fffu + ((x >> 16) & 1u)) >> 16;
    return (ushort_t)r;
}
__device__ __forceinline__ unsigned int fbits(float f) {
    union { float f; unsigned int i; } c; c.f = f; return c.i;
}

__device__ __forceinline__ f32x4 mfma_16x16x16_bf16(bf16x4 a, bf16x4 b, f32x4 c) {
#if __has_builtin(__builtin_amdgcn_mfma_f32_16x16x16bf16_1k)
    return __builtin_amdgcn_mfma_f32_16x16x16bf16_1k(a, b, c, 0, 0, 0);
#else
    f32x4 d;
    asm("v_mfma_f32_16x16x16_bf16 %0, %1, %2, %3" : "=v"(d) : "v"(a), "v"(b), "v"(c));
    return d;
#endif
}

#define AS1(p) ((const __attribute__((address_space(1))) void*)(p))
#define AS3(p) ((__attribute__((address_space(3))) void*)(p))

__device__ __forceinline__ void barrier_raw() {
    asm volatile("" ::: "memory");
    __builtin_amdgcn_s_barrier();
    asm volatile("" ::: "memory");
}

// ---------------- fp32 -> bf16 convert: 3 segments in one launch ----------------
__global__ __launch_bounds__(256) void convert3(const float* __restrict__ s0, ushort_t* __restrict__ d0, int nb0,
                                                const float* __restrict__ s1, ushort_t* __restrict__ d1, int nb1,
                                                const float* __restrict__ s2, ushort_t* __restrict__ d2) {
    int b = blockIdx.x;
    const float* s; ushort_t* d;
    if (b < nb0)            { s = s0; d = d0; }
    else if (b < nb0 + nb1) { s = s1; d = d1; b -= nb0; }
    else                    { s = s2; d = d2; b -= nb0 + nb1; }
    const int i = (b * 256 + threadIdx.x) * 4;
    const float4 v = *(const float4*)(s + i);
    d[i + 0] = f2bf(v.x);
    d[i + 1] = f2bf(v.y);
    d[i + 2] = f2bf(v.z);
    d[i + 3] = f2bf(v.w);
}

// ---------------- LayerNorm: one block per row (D=1024), fp32 in, bf16 out ----------------
__global__ __launch_bounds__(256) void ln_kernel(const float* __restrict__ x,
                                                 const float* __restrict__ g,
                                                 const float* __restrict__ be,
                                                 ushort_t* __restrict__ out) {
    const int row = blockIdx.x, tid = threadIdx.x;
    float v[4];
    #pragma unroll
    for (int j = 0; j < 4; ++j) v[j] = x[(size_t)row * D_ + tid + j * 256];
    float s = v[0] + v[1] + v[2] + v[3];
    #pragma unroll
    for (int o = 32; o > 0; o >>= 1) s += __shfl_xor(s, o);
    __shared__ float red1[4], red2[4];
    const int wid = tid >> 6, lane = tid & 63;
    if (lane == 0) red1[wid] = s;
    __syncthreads();
    const float mean = (red1[0] + red1[1] + red1[2] + red1[3]) * (1.0f / D_);
    float ss = 0.0f;
    #pragma unroll
    for (int j = 0; j < 4; ++j) { float d = v[j] - mean; ss += d * d; }
    #pragma unroll
    for (int o = 32; o > 0; o >>= 1) ss += __shfl_xor(ss, o);
    if (lane == 0) red2[wid] = ss;
    __syncthreads();
    const float var = (red2[0] + red2[1] + red2[2] + red2[3]) * (1.0f / D_);
    const float rs = rsqrtf(var + 1e-5f);
    #pragma unroll
    for (int j = 0; j < 4; ++j) {
        const int col = tid + j * 256;
        out[(size_t)row * D_ + col] = f2bf((v[j] - mean) * rs * g[col] + be[col]);
    }
}

// ---------------- GEMM 128x128, BK=64, 2 blocks/CU, 1 barrier + 1 vmcnt per K-tile ----------------
// R8 structure (best measured) + L2-banded block ordering:
// XCD chunk = 8 m-rows x ntn n-cols; iterate it in bands of NB=2 n-tiles (for band: for mi: for ni)
// -> per-XCD L2 working set = A-panel 2MB (resident across bands) + B-band 512KB.  B is read from
// L3 once per XCD instead of once per m-row (8x less L3/HBM panel traffic).
// Per K-tile: MFMA x32 ; vmcnt(0) (drains tile t+1, STAGEd a FULL tile earlier) ; barrier ;
// ds_read 16 frags(next) ; STAGE8(t+2).  Swizzle: chunk c of row r at c^(r&7); readers XOR same.
// EPI: 0 = bf16 out; 1 = gelu bf16 out; 2/5 = +f32 resid, f32 out; 3 = +f32 resid+bias f32 out
template<int EPI>
__global__ __launch_bounds__(256, 2) void gemm128(const ushort_t* __restrict__ A, int lda,
                                                  const ushort_t* __restrict__ W, int ldw,
                                                  const float* __restrict__ bias,
                                                  const float* __restrict__ resid,
                                                  void* __restrict__ Cout,
                                                  int Nn, int K, int ntn) {
    __shared__ ushort_t As[2 * 128 * 64];
    __shared__ ushort_t Bs[2 * 128 * 64];
    const int tid = threadIdx.x;
    // XCD chunk (blockIdx round-robins across 8 XCDs) + L2-banded within-chunk order.
    // chunk = nwg/8 = 8*ntn blocks = 8 m-rows x ntn n-cols for every grid in this file.
    const int xcd = blockIdx.x & 7;
    const int c   = blockIdx.x >> 3;          // within-chunk index, dispatch-ordered
    const int NB  = 2;                        // n-band width (B band = 512 KB, L2-resident)
    const int bnd = c / (8 * NB);
    const int r   = c % (8 * NB);
    const int mi  = r / NB, ni = bnd * NB + (r % NB);
    const int m0 = (xcd * 8 + mi) * 128, n0 = ni * 128;

    const int w = tid >> 6, lane = tid & 63;
    const int quad = lane >> 4, l15 = lane & 15;
    const int wr = (w >> 1) * 64, wc = (w & 1) * 64;
    const int c0sw = quad ^ (l15 & 7);

    // staging: 4 row-groups of 32 rows; thread covers row r0+32g, swizzled chunk csw
    const int r0 = tid >> 3;
    const int csw = (tid & 7) ^ (r0 & 7);
    const ushort_t* pA0 = A + (size_t)(m0 + r0) * lda + csw * 8;
    const ushort_t* pB0 = W + (size_t)(n0 + r0) * ldw + csw * 8;
    const size_t jA = (size_t)32 * lda, jB = (size_t)32 * ldw;

#define SA(bb, g, kk) __builtin_amdgcn_global_load_lds(AS1(pA0 + (size_t)(g) * jA + (kk)), \
        AS3(As + (size_t)(bb) * 8192 + (g) * 2048 + (size_t)tid * 8), 16, 0, 0)
#define SB(bb, g, kk) __builtin_amdgcn_global_load_lds(AS1(pB0 + (size_t)(g) * jB + (kk)), \
        AS3(Bs + (size_t)(bb) * 8192 + (g) * 2048 + (size_t)tid * 8), 16, 0, 0)
#define STAGE8(bb, kk) do { SA(bb, 0, kk); SA(bb, 1, kk); SA(bb, 2, kk); SA(bb, 3, kk); \
                            SB(bb, 0, kk); SB(bb, 1, kk); SB(bb, 2, kk); SB(bb, 3, kk); } while (0)
#define LDA_(base, mi_, d0, d1) do { \
    const ushort_t* p_ = (base) + (size_t)(wr + (mi_) * 16 + l15) * 64; \
    d0 = *(const short8*)(p_ + (c0sw << 3)); \
    d1 = *(const short8*)(p_ + ((c0sw ^ 4) << 3)); \
  } while (0)
#define LDB_(base, ni_, d0, d1) do { \
    const ushort_t* p_ = (base) + (size_t)(wc + (ni_) * 16 + l15) * 64; \
    d0 = *(const short8*)(p_ + (c0sw << 3)); \
    d1 = *(const short8*)(p_ + ((c0sw ^ 4) << 3)); \
  } while (0)
#define DSRALL(bb) do { \
    const ushort_t* Ab_ = As + (bb) * 8192; \
    const ushort_t* Bb_ = Bs + (bb) * 8192; \
    _Pragma("unroll") \
    for (int ni_ = 0; ni_ < 4; ++ni_) LDB_(Bb_, ni_, b0[ni_], b1[ni_]); \
    _Pragma("unroll") \
    for (int mi_ = 0; mi_ < 4; ++mi_) LDA_(Ab_, mi_, a0[mi_], a1[mi_]); \
  } while (0)
#define MFMA2(mA, mB) do { \
    __builtin_amdgcn_s_setprio(1); \
    _Pragma("unroll") \
    for (int ni_ = 0; ni_ < 4; ++ni_) { \
      acc[mA][ni_] = __builtin_amdgcn_mfma_f32_16x16x32_bf16(a0[mA], b0[ni_], acc[mA][ni_], 0, 0, 0); \
      acc[mA][ni_] = __builtin_amdgcn_mfma_f32_16x16x32_bf16(a1[mA], b1[ni_], acc[mA][ni_], 0, 0, 0); \
      acc[mB][ni_] = __builtin_amdgcn_mfma_f32_16x16x32_bf16(a0[mB], b0[ni_], acc[mB][ni_], 0, 0, 0); \
      acc[mB][ni_] = __builtin_amdgcn_mfma_f32_16x16x32_bf16(a1[mB], b1[ni_], acc[mB][ni_], 0, 0, 0); \
    } \
    __builtin_amdgcn_s_setprio(0); \
  } while (0)

    f32x4 acc[4][4] = {};
    const int NT = K >> 6;

    short8 a0[4], a1[4], b0[4], b1[4];   // full K-tile fragment set (16 x b128)

    // prologue: stage tile0, sync, read its frags, stage tile1
    STAGE8(0, 0);
    asm volatile("s_waitcnt vmcnt(0)" ::: "memory");
    __builtin_amdgcn_sched_barrier(0);
    barrier_raw();
    DSRALL(0);
    if (NT > 1) STAGE8(1, 64);

    for (int kt = 0; kt < NT; ++kt) {
        // compute tile kt from registers (compiler inserts lgkm waits before first use)
        MFMA2(0, 1);
        MFMA2(2, 3);
        if (kt + 1 < NT) {
            const int nb = (kt + 1) & 1;
            // STAGE8(kt+1) was issued a full K-tile ago -> drain is latency-covered
            asm volatile("s_waitcnt vmcnt(0)" ::: "memory");
            __builtin_amdgcn_sched_barrier(0);
            barrier_raw();      // collective: tile kt+1 writes visible; all waves done reading buf kt&1
            DSRALL(nb);
            if (kt + 2 < NT) STAGE8(kt & 1, (size_t)(kt + 2) * 64);
        }
    }

#undef SA
#undef SB
#undef STAGE8
#undef LDA_
#undef LDB_
#undef DSRALL
#undef MFMA2

    // ---- epilogue ----
    #pragma unroll
    for (int ni_ = 0; ni_ < 4; ++ni_) {
        const int col = n0 + wc + ni_ * 16 + l15;
        const float bv = (EPI == 5) ? 0.0f : bias[col];
        #pragma unroll
        for (int mi_ = 0; mi_ < 4; ++mi_) {
            #pragma unroll
            for (int rr = 0; rr < 4; ++rr) {
                const int rowg = m0 + wr + mi_ * 16 + quad * 4 + rr;
                const size_t idx = (size_t)rowg * Nn + col;
                float v = acc[mi_][ni_][rr] + bv;
                if (EPI == 1) {
                    // tanh-GELU via exp2: 0.5*(1+tanh(y)) = u/(u+1), u=e^{2y}
                    const float y = 0.7978845608028654f * (v + 0.044715f * v * v * v);
                    const float u = exp2f(fminf(2.8853900817779268f * y, 80.0f));
                    v = v * u * __builtin_amdgcn_rcpf(u + 1.0f);
                }
                if (EPI == 2 || EPI == 5 || EPI == 3) {
                    v += resid[idx];
                    ((float*)Cout)[idx] = v;
                } else {
                    ((ushort_t*)Cout)[idx] = f2bf(v);
                }
            }
        }
    }
}

// ---------------- RoPE on q,k + V transpose, reading stacked qkv [M,3072] ----------------
#define QSCL 0.18033688011112042f   // 0.125 * log2(e)
__global__ __launch_bounds__(256) void rope_reorder(const ushort_t* __restrict__ qkv,
                                                    ushort_t* __restrict__ q_rot,
                                                    ushort_t* __restrict__ k_rot,
                                                    ushort_t* __restrict__ v_t) {
    const int LD = 3 * D_;
    const int tt = blockIdx.x, h = blockIdx.y, b = blockIdx.z;
    const int t0 = tt * 64, tid = threadIdx.x;
    const int r = tid >> 2, c = tid & 3;
    const int t = t0 + r;
    const size_t src = ((size_t)(b * T_ + t)) * LD + h * DK + c * 16;
    const size_t dst = (((size_t)(b * NH + h)) * T_ + t) * DK + c * 16;
    #pragma unroll
    for (int j = 0; j < 8; ++j) {
        const int i = c * 8 + j;  // pair index 0..31
        const float theta = expf(-(float)(2 * i) * (1.0f / DK) * 9.210340371976184f);
        const float ang = (float)t * theta;
        float sn, cs;
        sincosf(ang, &sn, &cs);
        {
            float x1 = bf2f(qkv[src + 2 * j]), x2 = bf2f(qkv[src + 2 * j + 1]);
            q_rot[dst + 2 * j]     = f2bf((x1 * cs - x2 * sn) * QSCL);
            q_rot[dst + 2 * j + 1] = f2bf((x1 * sn + x2 * cs) * QSCL);
        }
        {
            float x1 = bf2f(qkv[src + D_ + 2 * j]), x2 = bf2f(qkv[src + D_ + 2 * j + 1]);
            k_rot[dst + 2 * j]     = f2bf(x1 * cs - x2 * sn);
            k_rot[dst + 2 * j + 1] = f2bf(x1 * sn + x2 * cs);
        }
    }
    // V transpose via LDS
    __shared__ ushort_t vs[64][72];
    #pragma unroll
    for (int j = 0; j < 16; ++j)
        vs[r][c * 16 + j] = qkv[((size_t)(b * T_ + t)) * LD + 2 * D_ + h * DK + c * 16 + j];
    __syncthreads();
    const int d = tid >> 2, tc = (tid & 3) * 16;
    const size_t vdst = (((size_t)(b * NH + h)) * DK + d) * T_ + t0 + tc;
    #pragma unroll
    for (int j = 0; j < 16; ++j)
        v_t[vdst + j] = vs[tc + j][d];
}

// ---------------- Flash attention: LDS-staged K/V, QBLK=128 (2 q-subtiles/wave) ----------------
__device__ __forceinline__ void softmax_tile(f32x4 (&st)[8], f32x4 (&oc)[4],
                                             float& mrow, float& lrow,
                                             unsigned int (&pk)[8][2]) {
    float mt[8];
    #pragma unroll
    for (int tl = 0; tl < 8; ++tl)
        mt[tl] = fmaxf(fmaxf(st[tl][0], st[tl][1]), fmaxf(st[tl][2], st[tl][3]));
    float mloc = fmaxf(fmaxf(fmaxf(mt[0], mt[1]), fmaxf(mt[2], mt[3])),
                       fmaxf(fmaxf(mt[4], mt[5]), fmaxf(mt[6], mt[7])));
    mloc = fmaxf(mloc, __shfl_xor(mloc, 16));
    mloc = fmaxf(mloc, __shfl_xor(mloc, 32));

    // defer-max: only rescale when the running max grew by >8 (log2 units)
    if (!__all(mloc <= mrow + 8.0f)) {
        const float mnew = fmaxf(mrow, mloc);
        const float al = exp2f(mrow - mnew);
        lrow *= al;
        #pragma unroll
        for (int ci = 0; ci < 4; ++ci)
            #pragma unroll
            for (int r = 0; r < 4; ++r) oc[ci][r] *= al;
        mrow = mnew;
    }

    float ps0 = 0.0f, ps1 = 0.0f;
    #pragma unroll
    for (int tl = 0; tl < 8; ++tl) {
        float p0 = exp2f(st[tl][0] - mrow);
        float p1 = exp2f(st[tl][1] - mrow);
        float p2 = exp2f(st[tl][2] - mrow);
        float p3 = exp2f(st[tl][3] - mrow);
        if (tl & 1) ps1 += (p0 + p1) + (p2 + p3);
        else        ps0 += (p0 + p1) + (p2 + p3);
        pk[tl][0] = (fbits(p1) & 0xFFFF0000u) | (fbits(p0) >> 16);
        pk[tl][1] = (fbits(p3) & 0xFFFF0000u) | (fbits(p2) >> 16);
    }
    float ps = ps0 + ps1;
    ps += __shfl_xor(ps, 16);
    ps += __shfl_xor(ps, 32);
    lrow += ps;
}

__global__ __launch_bounds__(256) void flash_attn(const ushort_t* __restrict__ q,
                                                  const ushort_t* __restrict__ k,
                                                  const ushort_t* __restrict__ vt,
                                                  ushort_t* __restrict__ ctx) {
    __shared__ ushort_t Ks[2 * 128 * 64];
    __shared__ ushort_t Vs[2 * 64 * 128];
    const int qt = blockIdx.x, h = blockIdx.y, b = blockIdx.z;
    const int tid = threadIdx.x, w = tid >> 6, lane = tid & 63;
    const int quad = lane >> 4, l15 = lane & 15;
    const int q0 = qt * 128;
    const size_t bh = (size_t)(b * NH + h);
    const ushort_t* qp = q + bh * T_ * DK;
    const ushort_t* kp = k + bh * T_ * DK;
    const ushort_t* vp = vt + bh * DK * T_;

    short8 qf[2][2];
    #pragma unroll
    for (int s = 0; s < 2; ++s)
        #pragma unroll
        for (int kk = 0; kk < 2; ++kk)
            qf[s][kk] = *(const short8*)(qp + (size_t)(q0 + w * 32 + s * 16 + l15) * DK + kk * 32 + quad * 8);

    f32x4 oc0[4] = {}, oc1[4] = {};
    float m0r = -INFINITY, l0r = 0.0f, m1r = -INFINITY, l1r = 0.0f;

    // staging source pointers (swizzle XOR is loop-invariant: rows advance by 128 == 0 mod 8)
    const ushort_t* ksp[4];
    const ushort_t* vsp[4];
    #pragma unroll
    for (int rr = 0; rr < 4; ++rr) {
        const int L = rr * 256 + tid;
        const int krow = L >> 3, kc = L & 7;
        ksp[rr] = kp + (size_t)krow * DK + ((kc ^ (krow & 7)) << 3);
        const int vrow = L >> 4, vc = L & 15;
        const int vsc = (vc & 8) | ((vc & 7) ^ (vrow & 7));
        vsp[rr] = vp + (size_t)vrow * T_ + (vsc << 3);
    }

#define STAGE(bufi) do {                                                                  \
        ushort_t* kb = Ks + (bufi) * (128 * 64);                                          \
        ushort_t* vb = Vs + (bufi) * (64 * 128);                                          \
        _Pragma("unroll")                                                                 \
        for (int rr = 0; rr < 4; ++rr) {                                                  \
            const int L = rr * 256 + tid;                                                 \
            __builtin_amdgcn_global_load_lds(AS1(ksp[rr]), AS3(kb + (size_t)L * 8), 16, 0, 0); \
            __builtin_amdgcn_global_load_lds(AS1(vsp[rr]), AS3(vb + (size_t)L * 8), 16, 0, 0); \
        }                                                                                 \
    } while (0)
#define ADVANCE() do {                                                                    \
        _Pragma("unroll")                                                                 \
        for (int rr = 0; rr < 4; ++rr) { ksp[rr] += 128 * DK; vsp[rr] += 128; }           \
    } while (0)

    STAGE(0); ADVANCE();
    __syncthreads();   // drains vmcnt(0) + barrier (compiler-inserted)

    int cur = 0;
    for (int it = 0; it < T_ / 128; ++it) {
        if (it + 1 < T_ / 128) { STAGE(cur ^ 1); ADVANCE(); }

        const ushort_t* kbase = Ks + cur * (128 * 64);
        const ushort_t* vbase = Vs + cur * (64 * 128);

        // QK^T: each K fragment read once, feeds both q-subtiles
        f32x4 st0[8], st1[8];
        __builtin_amdgcn_s_setprio(1);
        #pragma unroll
        for (int tl = 0; tl < 8; ++tl) {
            const int kvr = tl * 16 + l15;
            const int r7 = kvr & 7;
            const ushort_t* krow = kbase + (size_t)kvr * 64;
            short8 a0 = *(const short8*)(krow + ((quad ^ r7) << 3));
            short8 a1 = *(const short8*)(krow + (((quad + 4) ^ r7) << 3));
            f32x4 z0 = {};
            z0 = __builtin_amdgcn_mfma_f32_16x16x32_bf16(a0, qf[0][0], z0, 0, 0, 0);
            st0[tl] = __builtin_amdgcn_mfma_f32_16x16x32_bf16(a1, qf[0][1], z0, 0, 0, 0);
            f32x4 z1 = {};
            z1 = __builtin_amdgcn_mfma_f32_16x16x32_bf16(a0, qf[1][0], z1, 0, 0, 0);
            st1[tl] = __builtin_amdgcn_mfma_f32_16x16x32_bf16(a1, qf[1][1], z1, 0, 0, 0);
        }
        __builtin_amdgcn_s_setprio(0);

        unsigned int pk0[8][2], pk1[8][2];
        softmax_tile(st0, oc0, m0r, l0r, pk0);
        softmax_tile(st1, oc1, m1r, l1r, pk1);

        // PV: each V fragment read once, feeds both q-subtiles
        __builtin_amdgcn_s_setprio(1);
        #pragma unroll
        for (int t4 = 0; t4 < 8; ++t4) {
            union { unsigned int u[2]; bf16x4 v; } pb0, pb1;
            pb0.u[0] = pk0[t4][0]; pb0.u[1] = pk0[t4][1];
            pb1.u[0] = pk1[t4][0]; pb1.u[1] = pk1[t4][1];
            bf16x4 va[4];
            const int g = 2 * t4 + (quad >> 1);
            #pragma unroll
            for (int ci = 0; ci < 4; ++ci) {
                const int dd = ci * 16 + l15;
                const int sc = (g & 8) | ((g & 7) ^ (dd & 7));
                va[ci] = *(const bf16x4*)(vbase + (size_t)dd * 128 + (sc << 3) + ((quad & 1) << 2));
            }
            #pragma unroll
            for (int ci = 0; ci < 4; ++ci) {
                oc0[ci] = mfma_16x16x16_bf16(va[ci], pb0.v, oc0[ci]);
                oc1[ci] = mfma_16x16x16_bf16(va[ci], pb1.v, oc1[ci]);
            }
        }
        __builtin_amdgcn_s_setprio(0);

        __syncthreads();   // next-tile stage landed; all reads of cur done before overwrite
        cur ^= 1;
    }
#undef STAGE
#undef ADVANCE

    const float inv0 = 1.0f / l0r;
    const float inv1 = 1.0f / l1r;
    ushort_t* cb0 = ctx + (size_t)(b * T_ + q0 + w * 32 + l15) * D_ + h * DK + quad * 4;
    ushort_t* cb1 = ctx + (size_t)(b * T_ + q0 + w * 32 + 16 + l15) * D_ + h * DK + quad * 4;
    #pragma unroll
    for (int ci = 0; ci < 4; ++ci) {
        unsigned int u0 = ((unsigned int)f2bf(oc0[ci][0] * inv0)) | (((unsigned int)f2bf(oc0[ci][1] * inv0)) << 16);
        unsigned int u1 = ((unsigned int)f2bf(oc0[ci][2] * inv0)) | (((unsigned int)f2bf(oc0[ci][3] * inv0)) << 16);
        *(uint2*)(cb0 + ci * 16) = make_uint2(u0, u1);
        unsigned int u2 = ((unsigned int)f2bf(oc1[ci][0] * inv1)) | (((unsigned int)f2bf(oc1[ci][1] * inv1)) << 16);
        unsigned int u3 = ((unsigned int)f2bf(oc1[ci][2] * inv1)) | (((unsigned int)f2bf(oc1[ci][3] * inv1)) << 16);
        *(uint2*)(cb1 + ci * 16) = make_uint2(u2, u3);
    }
}

extern "C" void kernel_launch(void* const* d_in, const int* in_sizes, int n_in,
                              void* d_out, int out_size, void* d_ws, size_t ws_size,
                              hipStream_t stream) {
    const float* x   = (const float*)d_in[0];
    const float* Wq  = (const float*)d_in[2];
    const float* bq  = (const float*)d_in[3];
    const float* Wk  = (const float*)d_in[4];
    const float* bk  = (const float*)d_in[5];
    const float* Wv  = (const float*)d_in[6];
    const float* bv  = (const float*)d_in[7];
    const float* Wo  = (const float*)d_in[8];
    const float* bo  = (const float*)d_in[9];
    const float* W1  = (const float*)d_in[10];
    const float* b1  = (const float*)d_in[11];
    const float* W2  = (const float*)d_in[12];
    const float* b2  = (const float*)d_in[13];
    const float* g1  = (const float*)d_in[14];
    const float* be1 = (const float*)d_in[15];
    const float* g2  = (const float*)d_in[16];
    const float* be2 = (const float*)d_in[17];
    float* out = (float*)d_out;

    // ---- 96 MiB workspace layout ----
    // [0,48)  qkv_lin (48MB) -> ctx[0,16) + x2[16,48) after rope
    // [48,54) Wqkv_b (6MB, dead after QKV gemm) -> q_rot[48,64) -> Wo_b[48,50) -> ff[48,80)
    // [64,80) k_rot -> ff upper
    // [80,96) v_t -> W1_b[80,88) + W2_b[88,96)
    char* ws = (char*)d_ws;
    const size_t MB = 1024 * 1024;
    ushort_t* qkv_lin = (ushort_t*)(ws + 0 * MB);
    ushort_t* ctx     = (ushort_t*)(ws + 0 * MB);
    float*    x2      = (float*)   (ws + 16 * MB);
    ushort_t* Wqkv_b  = (ushort_t*)(ws + 48 * MB);
    ushort_t* q_rot   = (ushort_t*)(ws + 48 * MB);
    ushort_t* k_rot   = (ushort_t*)(ws + 64 * MB);
    ushort_t* v_t     = (ushort_t*)(ws + 80 * MB);
    ushort_t* Wo_b    = (ushort_t*)(ws + 48 * MB);
    ushort_t* ff      = (ushort_t*)(ws + 48 * MB);
    ushort_t* W1_b    = (ushort_t*)(ws + 80 * MB);
    ushort_t* W2_b    = (ushort_t*)(ws + 88 * MB);
    ushort_t* h1      = (ushort_t*)d_out;
    ushort_t* h2      = (ushort_t*)d_out;

    const int M = B_ * T_;
    const int DD = D_ * D_, DFD = DF_ * D_;

    // Phase A: LN1 + fused QKV (N=3072, stacked weights) — one convert launch for Wq/Wk/Wv
    convert3<<<3 * (DD / 1024), 256, 0, stream>>>(Wq, Wqkv_b, DD / 1024,
                                                  Wk, Wqkv_b + DD, DD / 1024,
                                                  Wv, Wqkv_b + 2 * DD);
    ln_kernel<<<M, 256, 0, stream>>>(x, g1, be1, h1);
    {
        float* bqkv = (float*)(ws + 54 * MB);  // 12 KB, dead after QKV gemm
        hipMemcpyAsync(bqkv,           bq, D_ * sizeof(float), hipMemcpyDeviceToDevice, stream);
        hipMemcpyAsync(bqkv + D_,      bk, D_ * sizeof(float), hipMemcpyDeviceToDevice, stream);
        hipMemcpyAsync(bqkv + 2 * D_,  bv, D_ * sizeof(float), hipMemcpyDeviceToDevice, stream);
        // grid 24*64 = 1536 blocks (%8==0)
        gemm128<0><<<(3072 / 128) * (M / 128), 256, 0, stream>>>(h1, D_, Wqkv_b, D_, bqkv, nullptr, qkv_lin, 3 * D_, D_, 3072 / 128);
    }

    // Phase B: RoPE + reorder (overwrites Wqkv_b region — dead)
    rope_reorder<<<dim3(T_ / 64, NH, B_), 256, 0, stream>>>(qkv_lin, q_rot, k_rot, v_t);

    // Phase C: attention (ctx overwrites qkv_lin lower 16MB — dead)
    flash_attn<<<dim3(T_ / 128, NH, B_), 256, 0, stream>>>(q_rot, k_rot, v_t, ctx);

    // Phase D: out-proj + residual; convert Wo/W1/W2 in ONE launch (v_t dead after flash)
    convert3<<<DD / 1024 + 2 * (DFD / 1024), 256, 0, stream>>>(Wo, Wo_b, DD / 1024,
                                                               W1, W1_b, DFD / 1024,
                                                               W2, W2_b);
    // grid 8*64 = 512 blocks (%8==0)
    gemm128<2><<<(D_ / 128) * (M / 128), 256, 0, stream>>>(ctx, D_, Wo_b, D_, bo, x, x2, D_, D_, D_ / 128);

    // Phase E: LN2
    ln_kernel<<<M, 256, 0, stream>>>(x2, g2, be2, h2);

    // Phase F: FFN in two DF halves (ff over q_rot/k_rot — dead)
    const int HF = DF_ / 2;
    // FFN1 halves: 16*64 = 1024 blocks; FFN2 halves: 8*64 = 512
    gemm128<1><<<(HF / 128) * (M / 128), 256, 0, stream>>>(h2, D_, W1_b, D_, b1, nullptr, ff, HF, D_, HF / 128);
    gemm128<5><<<(D_ / 128) * (M / 128), 256, 0, stream>>>(ff, HF, W2_b, DF_, nullptr, x2, x2, D_, HF, D_ / 128);
    gemm128<1><<<(HF / 128) * (M / 128), 256, 0, stream>>>(h2, D_, W1_b + (size_t)HF * D_, D_, b1 + HF, nullptr, ff, HF, D_, HF / 128);
    gemm128<3><<<(D_ / 128) * (M / 128), 256, 0, stream>>>(ff, HF, W2_b + HF, DF_, b2, x2, out, D_, HF, D_ / 128);
}